// Round 4
// baseline (133.461 us; speedup 1.0000x reference)
//
#include <hip/hip_runtime.h>
#include <hip/hip_bf16.h>

#define S0 480
#define S1 360
#define S2 32
#define SLAB (S1 * S2)                      // 11520
#define CH 32
#define EPS 1e-5f
#define SLOPE 0.01f

#define LOOKUP_INTS (2 * S0 * S1 * S2)      // 11,059,200
#define LOOKUP_BYTES ((size_t)LOOKUP_INTS * 4)
#define CHUNK 2048
#define NCHUNK (LOOKUP_INTS / CHUNK)        // 5400

typedef short short8 __attribute__((ext_vector_type(8)));
typedef float f32x16 __attribute__((ext_vector_type(16)));

__device__ __forceinline__ unsigned short f2b(float f) {
    union { __hip_bfloat16 b; unsigned short u; } v;
    v.b = __float2bfloat16(f);
    return v.u;
}

// ---- scatter: lookup[lin] = idx, plus per-chunk histogram ---------------
__global__ __launch_bounds__(256) void scatter_k(
    const int4* __restrict__ coords, int* __restrict__ lookup,
    int* __restrict__ ccount, int n)
{
    int i = blockIdx.x * 256 + threadIdx.x;
    if (i < n) {
        int4 c = coords[i];
        int lin = ((c.x * S0 + c.y) * S1 + c.z) * S2 + c.w;
        lookup[lin] = i;
        atomicAdd(&ccount[lin >> 11], 1);   // CHUNK = 2048
    }
}

// ---- exclusive scan over NCHUNK chunk counts (single block) -------------
__global__ __launch_bounds__(256) void scan_k(
    const int* __restrict__ ccount, int* __restrict__ cbase)
{
    const int PER = (NCHUNK + 255) / 256;   // 22
    int t = threadIdx.x;
    int tsum = 0;
    for (int j = 0; j < PER; ++j) {
        int idx = t * PER + j;
        if (idx < NCHUNK) tsum += ccount[idx];
    }
    __shared__ int sa[256], sb[256];
    sa[t] = tsum; __syncthreads();
    int* src = sa; int* dst = sb;
#pragma unroll
    for (int off = 1; off < 256; off <<= 1) {
        dst[t] = src[t] + (t >= off ? src[t - off] : 0);
        __syncthreads();
        int* tmp = src; src = dst; dst = tmp;
    }
    int running = src[t] - tsum;            // exclusive prefix
    for (int j = 0; j < PER; ++j) {
        int idx = t * PER + j;
        if (idx < NCHUNK) {
            cbase[idx] = running;
            running += ccount[idx];
        }
    }
}

// ---- fill: assign ranks, rewrite lookup, reorder features to bf16 -------
__global__ __launch_bounds__(256) void fill_k(
    const float* __restrict__ features,
    int* __restrict__ lookup,
    const int* __restrict__ cbase,
    int* __restrict__ orig,
    int* __restrict__ linS,
    unsigned short* __restrict__ featb)
{
    int blk = blockIdx.x;
    int t = threadIdx.x;
    int base_pos = blk * CHUNK + t * 8;

    const int4* lp = (const int4*)(lookup + base_pos);
    int4 v0 = lp[0], v1 = lp[1];
    int e[8] = { v0.x, v0.y, v0.z, v0.w, v1.x, v1.y, v1.z, v1.w };

    int tcnt = 0;
#pragma unroll
    for (int j = 0; j < 8; ++j) tcnt += (e[j] >= 0);

    __shared__ int sa[256], sb[256];
    sa[t] = tcnt; __syncthreads();
    int* src = sa; int* dst = sb;
#pragma unroll
    for (int off = 1; off < 256; off <<= 1) {
        dst[t] = src[t] + (t >= off ? src[t - off] : 0);
        __syncthreads();
        int* tmp = src; src = dst; dst = tmp;
    }
    int excl = src[t] - tcnt;

    __shared__ int s_idx[CHUNK];
    __shared__ int s_m;
    if (t == 255) s_m = src[255];

    int cb = cbase[blk];
    int local = excl;
#pragma unroll
    for (int j = 0; j < 8; ++j) {
        int idx = e[j];
        if (idx >= 0) {
            int pos = base_pos + j;
            int rank = cb + local;
            lookup[pos] = rank;
            orig[rank] = idx;
            linS[rank] = pos;
            s_idx[local] = idx;
            ++local;
        }
    }
    __syncthreads();

    // cooperative feature copy: 8 threads per row, coalesced
    int m = s_m;
    ushort4* fb4 = (ushort4*)featb;
    int j = t & 7;
    for (int bp = t >> 3; bp < m; bp += 32) {
        int idx = s_idx[bp];
        float4 f = ((const float4*)(features + (size_t)idx * CH))[j];
        ushort4 u;
        u.x = f2b(f.x); u.y = f2b(f.y); u.z = f2b(f.z); u.w = f2b(f.w);
        fb4[(size_t)(cb + bp) * 8 + j] = u;
    }
}

// ---- pre-pack weights into per-lane MFMA B fragments --------------------
__global__ void bfrag_prep_k(const float* __restrict__ weight,
                             short8* __restrict__ bfrag)
{
    int lane = threadIdx.x;          // 64 threads
    int half = lane >> 5;
    int col  = lane & 31;
#pragma unroll
    for (int t = 0; t < 9; ++t)
#pragma unroll
        for (int h = 0; h < 2; ++h) {
            short8 fr;
#pragma unroll
            for (int j = 0; j < 8; ++j) {
                int ic = h * 16 + half * 8 + j;
                fr[j] = (short)f2b(weight[t * (CH * CH) + ic * CH + col]);
            }
            bfrag[(t * 2 + h) * 64 + lane] = fr;
        }
}

// ---- conv on rank-sorted points: wave = 32 consecutive ranks ------------
__global__ __launch_bounds__(256) void conv_sorted_k(
    const unsigned short* __restrict__ featb,
    const int*  __restrict__ linS,
    const int*  __restrict__ lookup,
    const short8* __restrict__ bfrag,
    const int*  __restrict__ orig,
    float*      __restrict__ out,        // d_out, original row order
    float*      __restrict__ stats_part, // [gridDim.x][64]
    int n, int ntile)
{
    int tid  = threadIdx.x;
    int lane = tid & 63;
    int wv   = tid >> 6;
    int half = lane >> 5;
    int col  = lane & 31;

    short8 B[9][2];
#pragma unroll
    for (int t = 0; t < 9; ++t) {
        B[t][0] = bfrag[(t * 2 + 0) * 64 + lane];
        B[t][1] = bfrag[(t * 2 + 1) * 64 + lane];
    }

    int tile = blockIdx.x * 4 + wv;
    bool tlive = (tile < ntile);
    int p  = tile * 32 + col;
    bool live = tlive && (p < n);
    int pc = live ? p : 0;

    int lin = linS[pc];
    int myorig = live ? orig[pc] : 0;
    int c2 = lin & 31;
    int c0 = (lin / SLAB) % S0;

    // phase 1: 9 lookup gathers (near-contiguous lines in sorted order)
    int nbr[9];
#pragma unroll
    for (int d0 = 0; d0 < 3; ++d0) {
        int n0 = c0 + d0 - 1;
        bool v0 = (n0 >= 0) & (n0 < S0) & live;
#pragma unroll
        for (int d2 = 0; d2 < 3; ++d2) {
            int n2 = c2 + d2 - 1;
            bool v = v0 & (n2 >= 0) & (n2 < S2);
            nbr[d0 * 3 + d2] = v ? lookup[lin + (d0 - 1) * SLAB + (d2 - 1)] : -1;
        }
    }

    bool act[9];
#pragma unroll
    for (int t = 0; t < 9; ++t) act[t] = (__any(nbr[t] >= 0) != 0);

    // phase 2: staged bf16 fragment gathers (L1/L2-local after reorder)
    short8 A0[9], A1[9];
#pragma unroll
    for (int t = 0; t < 9; ++t) {
        short8 z;
#pragma unroll
        for (int j = 0; j < 8; ++j) z[j] = 0;
        A0[t] = z; A1[t] = z;
        int nb = nbr[t];
        if (nb >= 0) {
            const short* fp = (const short*)featb + (size_t)nb * CH;
            A0[t] = *(const short8*)(fp + half * 8);
            A1[t] = *(const short8*)(fp + 16 + half * 8);
        }
    }

    // phase 3: MFMAs, skipping wave-dead taps
    f32x16 acc;
#pragma unroll
    for (int r = 0; r < 16; ++r) acc[r] = 0.f;
#pragma unroll
    for (int t = 0; t < 9; ++t) {
        if (act[t]) {
            acc = __builtin_amdgcn_mfma_f32_32x32x16_bf16(A0[t], B[t][0], acc, 0, 0, 0);
            acc = __builtin_amdgcn_mfma_f32_32x32x16_bf16(A1[t], B[t][1], acc, 0, 0, 0);
        }
    }

    // epilogue: LeakyReLU + scatter fp32 rows to original order + stats
    // C/D layout: col = lane&31, row = (r&3) + 8*(r>>2) + 4*half
    float s = 0.f, q = 0.f;
#pragma unroll
    for (int r = 0; r < 16; ++r) {
        float v = acc[r];
        v = v >= 0.f ? v : SLOPE * v;
        int row = (r & 3) + 8 * (r >> 2) + 4 * half;
        int prow = tile * 32 + row;
        int orow = __shfl(myorig, row, 64);
        if (tlive && prow < n) {
            out[(size_t)orow * CH + col] = v;
            s += v; q += v * v;
        }
    }

    s += __shfl_xor(s, 32);
    q += __shfl_xor(q, 32);

    __shared__ float lsum[4][32];
    __shared__ float lsq[4][32];
    if (lane < 32) { lsum[wv][col] = s; lsq[wv][col] = q; }
    __syncthreads();
    if (tid < 32) {
        stats_part[(size_t)blockIdx.x * 64 + tid] =
            lsum[0][tid] + lsum[1][tid] + lsum[2][tid] + lsum[3][tid];
    } else if (tid < 64) {
        int cc = tid - 32;
        stats_part[(size_t)blockIdx.x * 64 + tid] =
            lsq[0][cc] + lsq[1][cc] + lsq[2][cc] + lsq[3][cc];
    }
}

// ---- deterministic partial reduce ---------------------------------------
__global__ __launch_bounds__(256) void reduce_stats_k(
    const float* __restrict__ part, float* __restrict__ stats, int nb)
{
    int c = blockIdx.x;            // 0..63
    float s = 0.f;
    for (int i = threadIdx.x; i < nb; i += 256)
        s += part[(size_t)i * 64 + c];
#pragma unroll
    for (int m = 32; m > 0; m >>= 1) s += __shfl_xor(s, m, 64);
    __shared__ float red[4];
    int wv = threadIdx.x >> 6;
    if ((threadIdx.x & 63) == 0) red[wv] = s;
    __syncthreads();
    if (threadIdx.x == 0) stats[c] = red[0] + red[1] + red[2] + red[3];
}

// ---- BN normalize in place on d_out -------------------------------------
__global__ __launch_bounds__(256) void bn_apply_k(
    float* __restrict__ x,
    const float* __restrict__ stats,
    const float* __restrict__ gamma,
    const float* __restrict__ beta,
    int n)
{
    int total4 = n * (CH / 4);
    int stride = gridDim.x * blockDim.x;   // multiple of 8
    int g = blockIdx.x * blockDim.x + threadIdx.x;
    int c4 = g & 7;

    float scale[4], shift[4];
    float rn = 1.0f / (float)n;
#pragma unroll
    for (int j = 0; j < 4; ++j) {
        int oc = c4 * 4 + j;
        float m  = stats[oc] * rn;
        float vv = stats[CH + oc] * rn - m * m;
        float iv = rsqrtf(vv + EPS) * gamma[oc];
        scale[j] = iv;
        shift[j] = beta[oc] - m * iv;
    }

    float4* x4 = (float4*)x;
    for (; g < total4; g += stride) {
        float4 v = x4[g];
        v.x = fmaf(v.x, scale[0], shift[0]);
        v.y = fmaf(v.y, scale[1], shift[1]);
        v.z = fmaf(v.z, scale[2], shift[2]);
        v.w = fmaf(v.w, scale[3], shift[3]);
        x4[g] = v;
    }
}

extern "C" void kernel_launch(void* const* d_in, const int* in_sizes, int n_in,
                              void* d_out, int out_size, void* d_ws, size_t ws_size,
                              hipStream_t stream)
{
    const float* features = (const float*)d_in[0];
    const int4*  coords   = (const int4*)d_in[1];
    const float* weight   = (const float*)d_in[2];
    const float* gamma    = (const float*)d_in[3];
    const float* beta     = (const float*)d_in[4];
    float* out = (float*)d_out;

    int n = in_sizes[0] / CH;            // 400000
    int ntile = (n + 31) / 32;           // 12500
    int conv_blocks = (ntile + 3) / 4;   // 3125

    // ws layout
    char* w = (char*)d_ws;
    int* lookup = (int*)w;                         w += LOOKUP_BYTES;          // 44.24 MB
    unsigned short* featb = (unsigned short*)w;    w += (size_t)n * CH * 2;    // 25.6 MB
    int* linS = (int*)w;                           w += (size_t)n * 4;         // 1.6 MB
    int* orig = (int*)w;                           w += (size_t)n * 4;         // 1.6 MB
    int* ccount = (int*)w;                         w += NCHUNK * 4;
    int* cbase = (int*)w;                          w += NCHUNK * 4;
    float* stats_part = (float*)w;                 w += (size_t)conv_blocks * 64 * 4;
    short8* bfrag = (short8*)w;                    w += 9 * 2 * 64 * sizeof(short8);
    float* stats = (float*)w;

    hipMemsetAsync(lookup, 0xFF, LOOKUP_BYTES, stream);
    hipMemsetAsync(ccount, 0, NCHUNK * 4, stream);

    scatter_k<<<(n + 255) / 256, 256, 0, stream>>>(coords, lookup, ccount, n);
    bfrag_prep_k<<<1, 64, 0, stream>>>(weight, bfrag);
    scan_k<<<1, 256, 0, stream>>>(ccount, cbase);
    fill_k<<<NCHUNK, 256, 0, stream>>>(features, lookup, cbase, orig, linS, featb);

    conv_sorted_k<<<conv_blocks, 256, 0, stream>>>(
        featb, linS, lookup, bfrag, orig, out, stats_part, n, ntile);

    reduce_stats_k<<<64, 256, 0, stream>>>(stats_part, stats, conv_blocks);

    bn_apply_k<<<2048, 256, 0, stream>>>(out, stats, gamma, beta, n);
}

// Round 5
// 114.648 us; speedup vs baseline: 1.1641x; 1.1641x over previous
//
#include <hip/hip_runtime.h>
#include <hip/hip_bf16.h>

#define S0 480
#define S1 360
#define S2 32
#define SLAB (S1 * S2)                 // 11520
#define CH 32
#define EPS 1e-5f
#define SLOPE 0.01f

#define NCOL (2 * S0 * S1)             // 345600 columns (b,c0,c1)
#define SCAN_BLKS (NCOL / 256)         // 1350

typedef short short8 __attribute__((ext_vector_type(8)));
typedef float f32x16 __attribute__((ext_vector_type(16)));

__device__ __forceinline__ unsigned short f2b(float f) {
    union { __hip_bfloat16 b; unsigned short u; } v;
    v.b = __float2bfloat16(f);
    return v.u;
}

// ---- scatter: set presence bit (atomicOr = order-independent) -----------
__global__ __launch_bounds__(256) void scatter_or_k(
    const int4* __restrict__ coords, unsigned int* __restrict__ mask, int n)
{
    int i = blockIdx.x * 256 + threadIdx.x;
    if (i < n) {
        int4 c = coords[i];
        int col = (c.x * S0 + c.y) * S1 + c.z;
        atomicOr(&mask[col], 1u << c.w);
    }
}

// ---- scanA: per-256-col block popcount sums -----------------------------
__global__ __launch_bounds__(256) void scanA_k(
    const unsigned int* __restrict__ mask, int* __restrict__ bsum)
{
    int t = threadIdx.x;
    int pc = __popc(mask[blockIdx.x * 256 + t]);
#pragma unroll
    for (int m = 32; m > 0; m >>= 1) pc += __shfl_xor(pc, m, 64);
    __shared__ int red[4];
    if ((t & 63) == 0) red[t >> 6] = pc;
    __syncthreads();
    if (t == 0) bsum[blockIdx.x] = red[0] + red[1] + red[2] + red[3];
}

// ---- scanB: exclusive scan of 1350 block sums (single block) ------------
__global__ __launch_bounds__(256) void scanB_k(
    const int* __restrict__ bsum, int* __restrict__ bbase)
{
    const int PER = (SCAN_BLKS + 255) / 256;   // 6
    int t = threadIdx.x;
    int loc[PER];
    int tsum = 0;
#pragma unroll
    for (int j = 0; j < PER; ++j) {
        int idx = t * PER + j;
        int v = (idx < SCAN_BLKS) ? bsum[idx] : 0;
        loc[j] = v; tsum += v;
    }
    __shared__ int sa[256], sb[256];
    sa[t] = tsum; __syncthreads();
    int* src = sa; int* dst = sb;
#pragma unroll
    for (int off = 1; off < 256; off <<= 1) {
        dst[t] = src[t] + (t >= off ? src[t - off] : 0);
        __syncthreads();
        int* tmp = src; src = dst; dst = tmp;
    }
    int running = src[t] - tsum;
#pragma unroll
    for (int j = 0; j < PER; ++j) {
        int idx = t * PER + j;
        if (idx < SCAN_BLKS) { bbase[idx] = running; running += loc[j]; }
    }
}

// ---- scanC: tab[col] = {mask, exclusive rank base} ----------------------
__global__ __launch_bounds__(256) void scanC_k(
    const unsigned int* __restrict__ mask, const int* __restrict__ bbase,
    uint2* __restrict__ tab)
{
    int t = threadIdx.x;
    int col = blockIdx.x * 256 + t;
    unsigned int m = mask[col];
    int pc = __popc(m);
    __shared__ int sa[256], sb[256];
    sa[t] = pc; __syncthreads();
    int* src = sa; int* dst = sb;
#pragma unroll
    for (int off = 1; off < 256; off <<= 1) {
        dst[t] = src[t] + (t >= off ? src[t - off] : 0);
        __syncthreads();
        int* tmp = src; src = dst; dst = tmp;
    }
    int excl = src[t] - pc + bbase[blockIdx.x];
    tab[col] = make_uint2(m, (unsigned int)excl);
}

// ---- fill: per-point rank, pinfo, bf16 feature reorder ------------------
__global__ __launch_bounds__(256) void fill_k(
    const float* __restrict__ features,
    const int4*  __restrict__ coords,
    const uint2* __restrict__ tab,
    uint2*       __restrict__ pinfo,     // [rank] = {orig_idx, lin}
    unsigned short* __restrict__ featb,  // [rank][32] bf16
    int n)
{
    int i = blockIdx.x * 256 + threadIdx.x;
    if (i >= n) return;
    int4 c = coords[i];
    int col = (c.x * S0 + c.y) * S1 + c.z;
    int lin = col * 32 + c.w;
    uint2 tv = tab[col];
    int rank = (int)tv.y + __popc(tv.x & ((1u << c.w) - 1u));
    pinfo[rank] = make_uint2((unsigned int)i, (unsigned int)lin);

    const float4* fp = (const float4*)(features + (size_t)i * CH);
    short8* fb = (short8*)(featb + (size_t)rank * CH);
#pragma unroll
    for (int h = 0; h < 4; ++h) {
        float4 a = fp[h * 2 + 0];
        float4 b = fp[h * 2 + 1];
        short8 u;
        u[0] = (short)f2b(a.x); u[1] = (short)f2b(a.y);
        u[2] = (short)f2b(a.z); u[3] = (short)f2b(a.w);
        u[4] = (short)f2b(b.x); u[5] = (short)f2b(b.y);
        u[6] = (short)f2b(b.z); u[7] = (short)f2b(b.w);
        fb[h] = u;
    }
}

// ---- pre-pack weights into per-lane MFMA B fragments --------------------
__global__ void bfrag_prep_k(const float* __restrict__ weight,
                             short8* __restrict__ bfrag)
{
    int lane = threadIdx.x;          // 64 threads
    int half = lane >> 5;
    int col  = lane & 31;
#pragma unroll
    for (int t = 0; t < 9; ++t)
#pragma unroll
        for (int h = 0; h < 2; ++h) {
            short8 fr;
#pragma unroll
            for (int j = 0; j < 8; ++j) {
                int ic = h * 16 + half * 8 + j;
                fr[j] = (short)f2b(weight[t * (CH * CH) + ic * CH + col]);
            }
            bfrag[(t * 2 + h) * 64 + lane] = fr;
        }
}

// ---- conv on rank-sorted points: wave = 32 consecutive ranks ------------
__global__ __launch_bounds__(256) void conv_sorted_k(
    const unsigned short* __restrict__ featb,
    const uint2* __restrict__ pinfo,
    const uint2* __restrict__ tab,
    const short8* __restrict__ bfrag,
    unsigned short* __restrict__ xout,   // bf16 x, rank order [n][32]
    float*        __restrict__ stats_part, // [gridDim.x][64]
    int n, int ntile)
{
    // bijective XCD-chunked swizzle (m204)
    int nwg = gridDim.x;
    int bid = blockIdx.x;
    int q = nwg >> 3, r = nwg & 7;
    int xcd = bid & 7, sidx = bid >> 3;
    int blk = (xcd < r ? xcd * (q + 1) : r * (q + 1) + (xcd - r) * q) + sidx;

    int tid  = threadIdx.x;
    int lane = tid & 63;
    int wv   = tid >> 6;
    int half = lane >> 5;
    int col  = lane & 31;

    short8 B[9][2];
#pragma unroll
    for (int t = 0; t < 9; ++t) {
        B[t][0] = bfrag[(t * 2 + 0) * 64 + lane];
        B[t][1] = bfrag[(t * 2 + 1) * 64 + lane];
    }

    int tile = blk * 4 + wv;
    bool tlive = (tile < ntile);
    int p  = tile * 32 + col;
    bool live = tlive && (p < n);
    int pc = live ? p : 0;

    uint2 pi = pinfo[pc];
    int lin = (int)pi.y;
    int c2 = lin & 31;
    int colv = lin >> 5;
    int c0 = (lin / SLAB) % S0;

    // phase 1: 3 table loads (2.76 MB, L2-resident) -> 9 ranks via popcount
    int nbr[9];
#pragma unroll
    for (int d0 = 0; d0 < 3; ++d0) {
        int n0 = c0 + d0 - 1;
        bool v0 = (n0 >= 0) & (n0 < S0) & live;
        uint2 tv = v0 ? tab[colv + (d0 - 1) * S1] : make_uint2(0u, 0u);
#pragma unroll
        for (int d2 = 0; d2 < 3; ++d2) {
            int n2 = c2 + d2 - 1;
            int rk = -1;
            if (v0 && n2 >= 0 && n2 < S2 && ((tv.x >> n2) & 1u))
                rk = (int)tv.y + __popc(tv.x & ((1u << n2) - 1u));
            nbr[d0 * 3 + d2] = rk;
        }
    }

    bool act[9];
#pragma unroll
    for (int t = 0; t < 9; ++t) act[t] = (__any(nbr[t] >= 0) != 0);

    // phase 2: staged bf16 fragment gathers (rank-local after sort)
    short8 A0[9], A1[9];
#pragma unroll
    for (int t = 0; t < 9; ++t) {
        short8 z;
#pragma unroll
        for (int j = 0; j < 8; ++j) z[j] = 0;
        A0[t] = z; A1[t] = z;
        int nb = nbr[t];
        if (nb >= 0) {
            const short* fp = (const short*)featb + (size_t)nb * CH;
            A0[t] = *(const short8*)(fp + half * 8);
            A1[t] = *(const short8*)(fp + 16 + half * 8);
        }
    }

    // phase 3: MFMAs, skipping wave-dead taps
    f32x16 acc;
#pragma unroll
    for (int i = 0; i < 16; ++i) acc[i] = 0.f;
#pragma unroll
    for (int t = 0; t < 9; ++t) {
        if (act[t]) {
            acc = __builtin_amdgcn_mfma_f32_32x32x16_bf16(A0[t], B[t][0], acc, 0, 0, 0);
            acc = __builtin_amdgcn_mfma_f32_32x32x16_bf16(A1[t], B[t][1], acc, 0, 0, 0);
        }
    }

    // epilogue: LeakyReLU + bf16 coalesced store (rank order) + stats
    // C/D layout: col = lane&31, row = (r&3) + 8*(r>>2) + 4*half
    float s = 0.f, qq = 0.f;
#pragma unroll
    for (int i = 0; i < 16; ++i) {
        float v = acc[i];
        v = v >= 0.f ? v : SLOPE * v;
        int row = (i & 3) + 8 * (i >> 2) + 4 * half;
        int prow = tile * 32 + row;
        if (tlive && prow < n) {
            xout[(size_t)prow * CH + col] = f2b(v);
            s += v; qq += v * v;
        }
    }

    s  += __shfl_xor(s, 32);
    qq += __shfl_xor(qq, 32);

    __shared__ float lsum[4][32];
    __shared__ float lsq[4][32];
    if (lane < 32) { lsum[wv][col] = s; lsq[wv][col] = qq; }
    __syncthreads();
    if (tid < 32) {
        stats_part[(size_t)bid * 64 + tid] =
            lsum[0][tid] + lsum[1][tid] + lsum[2][tid] + lsum[3][tid];
    } else if (tid < 64) {
        int cc = tid - 32;
        stats_part[(size_t)bid * 64 + tid] =
            lsq[0][cc] + lsq[1][cc] + lsq[2][cc] + lsq[3][cc];
    }
}

// ---- deterministic partial reduce ---------------------------------------
__global__ __launch_bounds__(256) void reduce_stats_k(
    const float* __restrict__ part, float* __restrict__ stats, int nb)
{
    int c = blockIdx.x;            // 0..63
    float s = 0.f;
    for (int i = threadIdx.x; i < nb; i += 256)
        s += part[(size_t)i * 64 + c];
#pragma unroll
    for (int m = 32; m > 0; m >>= 1) s += __shfl_xor(s, m, 64);
    __shared__ float red[4];
    int wv = threadIdx.x >> 6;
    if ((threadIdx.x & 63) == 0) red[wv] = s;
    __syncthreads();
    if (threadIdx.x == 0) stats[c] = red[0] + red[1] + red[2] + red[3];
}

// ---- BN normalize: bf16 rank-order x -> fp32 out (original order) -------
__global__ __launch_bounds__(256) void bn_apply_k(
    const unsigned short* __restrict__ xb,
    const uint2* __restrict__ pinfo,
    const float* __restrict__ stats,
    const float* __restrict__ gamma,
    const float* __restrict__ beta,
    float* __restrict__ out,
    int n)
{
    int total = n * 4;                        // groups of 8 channels
    int stride = gridDim.x * blockDim.x;      // multiple of 4
    int g = blockIdx.x * blockDim.x + threadIdx.x;
    int c8 = g & 3;

    float scale[8], shift[8];
    float rn = 1.0f / (float)n;
#pragma unroll
    for (int j = 0; j < 8; ++j) {
        int oc = c8 * 8 + j;
        float m  = stats[oc] * rn;
        float vv = stats[CH + oc] * rn - m * m;
        float iv = rsqrtf(vv + EPS) * gamma[oc];
        scale[j] = iv;
        shift[j] = beta[oc] - m * iv;
    }

    const short8* x8 = (const short8*)xb;
    for (; g < total; g += stride) {
        int rank = g >> 2;
        unsigned int orig = pinfo[rank].x;
        short8 v = x8[g];
        float f[8];
#pragma unroll
        for (int j = 0; j < 8; ++j) {
            union { unsigned int u; float f; } w;
            w.u = ((unsigned int)(unsigned short)v[j]) << 16;
            f[j] = fmaf(w.f, scale[j], shift[j]);
        }
        float4* o = (float4*)(out + (size_t)orig * CH + c8 * 8);
        o[0] = make_float4(f[0], f[1], f[2], f[3]);
        o[1] = make_float4(f[4], f[5], f[6], f[7]);
    }
}

extern "C" void kernel_launch(void* const* d_in, const int* in_sizes, int n_in,
                              void* d_out, int out_size, void* d_ws, size_t ws_size,
                              hipStream_t stream)
{
    const float* features = (const float*)d_in[0];
    const int4*  coords   = (const int4*)d_in[1];
    const float* weight   = (const float*)d_in[2];
    const float* gamma    = (const float*)d_in[3];
    const float* beta     = (const float*)d_in[4];
    float* out = (float*)d_out;

    int n = in_sizes[0] / CH;            // 400000
    int ntile = (n + 31) / 32;           // 12500
    int conv_blocks = (ntile + 3) / 4;   // 3125

    // ws layout (256 B aligned sections)
    char* w = (char*)d_ws;
    unsigned int* mask = (unsigned int*)w;  w += (size_t)NCOL * 4;            // 1.38 MB
    uint2* tab = (uint2*)w;                 w += (size_t)NCOL * 8;            // 2.76 MB
    int* bsum = (int*)w;                    w += ((size_t)SCAN_BLKS * 4 + 255) & ~(size_t)255;
    int* bbase = (int*)w;                   w += ((size_t)SCAN_BLKS * 4 + 255) & ~(size_t)255;
    uint2* pinfo = (uint2*)w;               w += (size_t)n * 8;               // 3.2 MB
    unsigned short* featb = (unsigned short*)w; w += (size_t)n * CH * 2;      // 25.6 MB
    unsigned short* xout = (unsigned short*)w;  w += (size_t)n * CH * 2;      // 25.6 MB
    float* stats_part = (float*)w;          w += (size_t)conv_blocks * 64 * 4;
    short8* bfrag = (short8*)w;             w += 9 * 2 * 64 * sizeof(short8);
    float* stats = (float*)w;

    hipMemsetAsync(mask, 0, (size_t)NCOL * 4, stream);

    scatter_or_k<<<(n + 255) / 256, 256, 0, stream>>>(coords, mask, n);
    bfrag_prep_k<<<1, 64, 0, stream>>>(weight, bfrag);
    scanA_k<<<SCAN_BLKS, 256, 0, stream>>>(mask, bsum);
    scanB_k<<<1, 256, 0, stream>>>(bsum, bbase);
    scanC_k<<<SCAN_BLKS, 256, 0, stream>>>(mask, bbase, tab);
    fill_k<<<(n + 255) / 256, 256, 0, stream>>>(features, coords, tab, pinfo, featb, n);

    conv_sorted_k<<<conv_blocks, 256, 0, stream>>>(
        featb, pinfo, tab, bfrag, xout, stats_part, n, ntile);

    reduce_stats_k<<<64, 256, 0, stream>>>(stats_part, stats, conv_blocks);

    bn_apply_k<<<2048, 256, 0, stream>>>(xout, pinfo, stats, gamma, beta, out, n);
}

// Round 6
// 112.832 us; speedup vs baseline: 1.1828x; 1.0161x over previous
//
#include <hip/hip_runtime.h>
#include <hip/hip_bf16.h>

#define S0 480
#define S1 360
#define S2 32
#define SLAB (S1 * S2)                 // 11520
#define CH 32
#define EPS 1e-5f
#define SLOPE 0.01f

#define NCOL (2 * S0 * S1)             // 345600 columns (b,c0,c1)
#define SCAN_BLKS (NCOL / 256)         // 1350

typedef short short8 __attribute__((ext_vector_type(8)));
typedef float f32x16 __attribute__((ext_vector_type(16)));

__device__ __forceinline__ unsigned short f2b(float f) {
    union { __hip_bfloat16 b; unsigned short u; } v;
    v.b = __float2bfloat16(f);
    return v.u;
}

// ---- scatter: set presence bit (atomicOr = order-independent) -----------
__global__ __launch_bounds__(256) void scatter_or_k(
    const int4* __restrict__ coords, unsigned int* __restrict__ mask, int n)
{
    int i = blockIdx.x * 256 + threadIdx.x;
    if (i < n) {
        int4 c = coords[i];
        int col = (c.x * S0 + c.y) * S1 + c.z;
        atomicOr(&mask[col], 1u << c.w);
    }
}

// ---- scanA: per-256-col block popcount sums -----------------------------
__global__ __launch_bounds__(256) void scanA_k(
    const unsigned int* __restrict__ mask, int* __restrict__ bsum)
{
    int t = threadIdx.x;
    int pc = __popc(mask[blockIdx.x * 256 + t]);
#pragma unroll
    for (int m = 32; m > 0; m >>= 1) pc += __shfl_xor(pc, m, 64);
    __shared__ int red[4];
    if ((t & 63) == 0) red[t >> 6] = pc;
    __syncthreads();
    if (t == 0) bsum[blockIdx.x] = red[0] + red[1] + red[2] + red[3];
}

// ---- scanB: exclusive scan of 1350 block sums (single block) ------------
__global__ __launch_bounds__(256) void scanB_k(
    const int* __restrict__ bsum, int* __restrict__ bbase)
{
    const int PER = (SCAN_BLKS + 255) / 256;   // 6
    int t = threadIdx.x;
    int loc[PER];
    int tsum = 0;
#pragma unroll
    for (int j = 0; j < PER; ++j) {
        int idx = t * PER + j;
        int v = (idx < SCAN_BLKS) ? bsum[idx] : 0;
        loc[j] = v; tsum += v;
    }
    __shared__ int sa[256], sb[256];
    sa[t] = tsum; __syncthreads();
    int* src = sa; int* dst = sb;
#pragma unroll
    for (int off = 1; off < 256; off <<= 1) {
        dst[t] = src[t] + (t >= off ? src[t - off] : 0);
        __syncthreads();
        int* tmp = src; src = dst; dst = tmp;
    }
    int running = src[t] - tsum;
#pragma unroll
    for (int j = 0; j < PER; ++j) {
        int idx = t * PER + j;
        if (idx < SCAN_BLKS) { bbase[idx] = running; running += loc[j]; }
    }
}

// ---- scanC: tab[col] = {mask, exclusive rank base} ----------------------
__global__ __launch_bounds__(256) void scanC_k(
    const unsigned int* __restrict__ mask, const int* __restrict__ bbase,
    uint2* __restrict__ tab)
{
    int t = threadIdx.x;
    int col = blockIdx.x * 256 + t;
    unsigned int m = mask[col];
    int pc = __popc(m);
    __shared__ int sa[256], sb[256];
    sa[t] = pc; __syncthreads();
    int* src = sa; int* dst = sb;
#pragma unroll
    for (int off = 1; off < 256; off <<= 1) {
        dst[t] = src[t] + (t >= off ? src[t - off] : 0);
        __syncthreads();
        int* tmp = src; src = dst; dst = tmp;
    }
    int excl = src[t] - pc + bbase[blockIdx.x];
    tab[col] = make_uint2(m, (unsigned int)excl);
}

// ---- rank: per-point rank + pinfo (scattered 8B into L2-resident 3.2MB) -
__global__ __launch_bounds__(256) void rank_k(
    const int4*  __restrict__ coords,
    const uint2* __restrict__ tab,
    uint2*       __restrict__ pinfo,     // [rank] = {orig_idx, lin}
    int n)
{
    int i = blockIdx.x * 256 + threadIdx.x;
    if (i >= n) return;
    int4 c = coords[i];
    int col = (c.x * S0 + c.y) * S1 + c.z;
    int lin = col * 32 + c.w;
    uint2 tv = tab[col];
    int rank = (int)tv.y + __popc(tv.x & ((1u << c.w) - 1u));
    pinfo[rank] = make_uint2((unsigned int)i, (unsigned int)lin);
}

// ---- pack: coalesced featb write, full-line scattered feature reads -----
__global__ __launch_bounds__(256) void pack_k(
    const float* __restrict__ features,
    const uint2* __restrict__ pinfo,
    unsigned short* __restrict__ featb,  // [rank][32] bf16
    int n)
{
    int t = threadIdx.x;
    int row = blockIdx.x * 32 + (t >> 3);   // 32 rows per block
    int j = t & 7;                          // 8 lanes x 16B = one 128B row
    if (row >= n) return;
    unsigned int orig = pinfo[row].x;
    float4 f = ((const float4*)(features + (size_t)orig * CH))[j];
    ushort4 u;
    u.x = f2b(f.x); u.y = f2b(f.y); u.z = f2b(f.z); u.w = f2b(f.w);
    ((ushort4*)(featb + (size_t)row * CH))[j] = u;
}

// ---- pre-pack weights into per-lane MFMA B fragments --------------------
__global__ void bfrag_prep_k(const float* __restrict__ weight,
                             short8* __restrict__ bfrag)
{
    int lane = threadIdx.x;          // 64 threads
    int half = lane >> 5;
    int col  = lane & 31;
#pragma unroll
    for (int t = 0; t < 9; ++t)
#pragma unroll
        for (int h = 0; h < 2; ++h) {
            short8 fr;
#pragma unroll
            for (int j = 0; j < 8; ++j) {
                int ic = h * 16 + half * 8 + j;
                fr[j] = (short)f2b(weight[t * (CH * CH) + ic * CH + col]);
            }
            bfrag[(t * 2 + h) * 64 + lane] = fr;
        }
}

// ---- conv on rank-sorted points: wave = 32 consecutive ranks ------------
__global__ __launch_bounds__(256) void conv_sorted_k(
    const unsigned short* __restrict__ featb,
    const uint2* __restrict__ pinfo,
    const uint2* __restrict__ tab,
    const short8* __restrict__ bfrag,
    unsigned short* __restrict__ xout,   // bf16 x, rank order [n][32]
    float*        __restrict__ stats_part, // [gridDim.x][64]
    int n, int ntile)
{
    // bijective XCD-chunked swizzle (m204)
    int nwg = gridDim.x;
    int bid = blockIdx.x;
    int q = nwg >> 3, r = nwg & 7;
    int xcd = bid & 7, sidx = bid >> 3;
    int blk = (xcd < r ? xcd * (q + 1) : r * (q + 1) + (xcd - r) * q) + sidx;

    int tid  = threadIdx.x;
    int lane = tid & 63;
    int wv   = tid >> 6;
    int half = lane >> 5;
    int col  = lane & 31;

    short8 B[9][2];
#pragma unroll
    for (int t = 0; t < 9; ++t) {
        B[t][0] = bfrag[(t * 2 + 0) * 64 + lane];
        B[t][1] = bfrag[(t * 2 + 1) * 64 + lane];
    }

    int tile = blk * 4 + wv;
    bool tlive = (tile < ntile);
    int p  = tile * 32 + col;
    bool live = tlive && (p < n);
    int pc = live ? p : 0;

    uint2 pi = pinfo[pc];
    int lin = (int)pi.y;
    int c2 = lin & 31;
    int colv = lin >> 5;
    int c0 = (lin / SLAB) % S0;

    // phase 1: 3 table loads (2.76 MB, L2-resident) -> 9 ranks via popcount
    int nbr[9];
#pragma unroll
    for (int d0 = 0; d0 < 3; ++d0) {
        int n0 = c0 + d0 - 1;
        bool v0 = (n0 >= 0) & (n0 < S0) & live;
        uint2 tv = v0 ? tab[colv + (d0 - 1) * S1] : make_uint2(0u, 0u);
#pragma unroll
        for (int d2 = 0; d2 < 3; ++d2) {
            int n2 = c2 + d2 - 1;
            int rk = -1;
            if (v0 && n2 >= 0 && n2 < S2 && ((tv.x >> n2) & 1u))
                rk = (int)tv.y + __popc(tv.x & ((1u << n2) - 1u));
            nbr[d0 * 3 + d2] = rk;
        }
    }

    bool act[9];
#pragma unroll
    for (int t = 0; t < 9; ++t) act[t] = (__any(nbr[t] >= 0) != 0);

    // phase 2: staged bf16 fragment gathers (rank-local after sort)
    short8 A0[9], A1[9];
#pragma unroll
    for (int t = 0; t < 9; ++t) {
        short8 z;
#pragma unroll
        for (int j = 0; j < 8; ++j) z[j] = 0;
        A0[t] = z; A1[t] = z;
        int nb = nbr[t];
        if (nb >= 0) {
            const short* fp = (const short*)featb + (size_t)nb * CH;
            A0[t] = *(const short8*)(fp + half * 8);
            A1[t] = *(const short8*)(fp + 16 + half * 8);
        }
    }

    // phase 3: MFMAs, skipping wave-dead taps
    f32x16 acc;
#pragma unroll
    for (int i = 0; i < 16; ++i) acc[i] = 0.f;
#pragma unroll
    for (int t = 0; t < 9; ++t) {
        if (act[t]) {
            acc = __builtin_amdgcn_mfma_f32_32x32x16_bf16(A0[t], B[t][0], acc, 0, 0, 0);
            acc = __builtin_amdgcn_mfma_f32_32x32x16_bf16(A1[t], B[t][1], acc, 0, 0, 0);
        }
    }

    // epilogue: LeakyReLU + bf16 coalesced store (rank order) + stats
    // C/D layout: col = lane&31, row = (r&3) + 8*(r>>2) + 4*half
    float s = 0.f, qq = 0.f;
#pragma unroll
    for (int i = 0; i < 16; ++i) {
        float v = acc[i];
        v = v >= 0.f ? v : SLOPE * v;
        int row = (i & 3) + 8 * (i >> 2) + 4 * half;
        int prow = tile * 32 + row;
        if (tlive && prow < n) {
            xout[(size_t)prow * CH + col] = f2b(v);
            s += v; qq += v * v;
        }
    }

    s  += __shfl_xor(s, 32);
    qq += __shfl_xor(qq, 32);

    __shared__ float lsum[4][32];
    __shared__ float lsq[4][32];
    if (lane < 32) { lsum[wv][col] = s; lsq[wv][col] = qq; }
    __syncthreads();
    if (tid < 32) {
        stats_part[(size_t)bid * 64 + tid] =
            lsum[0][tid] + lsum[1][tid] + lsum[2][tid] + lsum[3][tid];
    } else if (tid < 64) {
        int cc = tid - 32;
        stats_part[(size_t)bid * 64 + tid] =
            lsq[0][cc] + lsq[1][cc] + lsq[2][cc] + lsq[3][cc];
    }
}

// ---- deterministic partial reduce ---------------------------------------
__global__ __launch_bounds__(256) void reduce_stats_k(
    const float* __restrict__ part, float* __restrict__ stats, int nb)
{
    int c = blockIdx.x;            // 0..63
    float s = 0.f;
    for (int i = threadIdx.x; i < nb; i += 256)
        s += part[(size_t)i * 64 + c];
#pragma unroll
    for (int m = 32; m > 0; m >>= 1) s += __shfl_xor(s, m, 64);
    __shared__ float red[4];
    int wv = threadIdx.x >> 6;
    if ((threadIdx.x & 63) == 0) red[wv] = s;
    __syncthreads();
    if (threadIdx.x == 0) stats[c] = red[0] + red[1] + red[2] + red[3];
}

// ---- BN normalize: bf16 rank-order x -> fp32 out (original order) -------
__global__ __launch_bounds__(256) void bn_apply_k(
    const unsigned short* __restrict__ xb,
    const uint2* __restrict__ pinfo,
    const float* __restrict__ stats,
    const float* __restrict__ gamma,
    const float* __restrict__ beta,
    float* __restrict__ out,
    int n)
{
    int total = n * 4;                        // groups of 8 channels
    int stride = gridDim.x * blockDim.x;      // multiple of 4
    int g = blockIdx.x * blockDim.x + threadIdx.x;
    int c8 = g & 3;

    float scale[8], shift[8];
    float rn = 1.0f / (float)n;
#pragma unroll
    for (int j = 0; j < 8; ++j) {
        int oc = c8 * 8 + j;
        float m  = stats[oc] * rn;
        float vv = stats[CH + oc] * rn - m * m;
        float iv = rsqrtf(vv + EPS) * gamma[oc];
        scale[j] = iv;
        shift[j] = beta[oc] - m * iv;
    }

    const short8* x8 = (const short8*)xb;
    for (; g < total; g += stride) {
        int rank = g >> 2;
        unsigned int orig = pinfo[rank].x;
        short8 v = x8[g];
        float f[8];
#pragma unroll
        for (int j = 0; j < 8; ++j) {
            union { unsigned int u; float f; } w;
            w.u = ((unsigned int)(unsigned short)v[j]) << 16;
            f[j] = fmaf(w.f, scale[j], shift[j]);
        }
        float4* o = (float4*)(out + (size_t)orig * CH + c8 * 8);
        o[0] = make_float4(f[0], f[1], f[2], f[3]);
        o[1] = make_float4(f[4], f[5], f[6], f[7]);
    }
}

extern "C" void kernel_launch(void* const* d_in, const int* in_sizes, int n_in,
                              void* d_out, int out_size, void* d_ws, size_t ws_size,
                              hipStream_t stream)
{
    const float* features = (const float*)d_in[0];
    const int4*  coords   = (const int4*)d_in[1];
    const float* weight   = (const float*)d_in[2];
    const float* gamma    = (const float*)d_in[3];
    const float* beta     = (const float*)d_in[4];
    float* out = (float*)d_out;

    int n = in_sizes[0] / CH;            // 400000
    int ntile = (n + 31) / 32;           // 12500
    int conv_blocks = (ntile + 3) / 4;   // 3125

    // ws layout (256 B aligned sections)
    char* w = (char*)d_ws;
    unsigned int* mask = (unsigned int*)w;  w += (size_t)NCOL * 4;            // 1.38 MB
    uint2* tab = (uint2*)w;                 w += (size_t)NCOL * 8;            // 2.76 MB
    int* bsum = (int*)w;                    w += ((size_t)SCAN_BLKS * 4 + 255) & ~(size_t)255;
    int* bbase = (int*)w;                   w += ((size_t)SCAN_BLKS * 4 + 255) & ~(size_t)255;
    uint2* pinfo = (uint2*)w;               w += (size_t)n * 8;               // 3.2 MB
    unsigned short* featb = (unsigned short*)w; w += (size_t)n * CH * 2;      // 25.6 MB
    unsigned short* xout = (unsigned short*)w;  w += (size_t)n * CH * 2;      // 25.6 MB
    float* stats_part = (float*)w;          w += (size_t)conv_blocks * 64 * 4;
    short8* bfrag = (short8*)w;             w += 9 * 2 * 64 * sizeof(short8);
    float* stats = (float*)w;

    hipMemsetAsync(mask, 0, (size_t)NCOL * 4, stream);

    scatter_or_k<<<(n + 255) / 256, 256, 0, stream>>>(coords, mask, n);
    bfrag_prep_k<<<1, 64, 0, stream>>>(weight, bfrag);
    scanA_k<<<SCAN_BLKS, 256, 0, stream>>>(mask, bsum);
    scanB_k<<<1, 256, 0, stream>>>(bsum, bbase);
    scanC_k<<<SCAN_BLKS, 256, 0, stream>>>(mask, bbase, tab);
    rank_k<<<(n + 255) / 256, 256, 0, stream>>>(coords, tab, pinfo, n);
    pack_k<<<(n + 31) / 32, 256, 0, stream>>>(features, pinfo, featb, n);

    conv_sorted_k<<<conv_blocks, 256, 0, stream>>>(
        featb, pinfo, tab, bfrag, xout, stats_part, n, ntile);

    reduce_stats_k<<<64, 256, 0, stream>>>(stats_part, stats, conv_blocks);

    bn_apply_k<<<2048, 256, 0, stream>>>(xout, pinfo, stats, gamma, beta, out, n);
}

// Round 7
// 112.570 us; speedup vs baseline: 1.1856x; 1.0023x over previous
//
#include <hip/hip_runtime.h>
#include <hip/hip_bf16.h>

#define S0 480
#define S1 360
#define S2 32
#define SLAB (S1 * S2)                 // 11520
#define CH 32
#define EPS 1e-5f
#define SLOPE 0.01f

#define NCOL (2 * S0 * S1)             // 345600 columns (b,c0,c1)
#define SCAN_BLKS (NCOL / 256)         // 1350

typedef short short8 __attribute__((ext_vector_type(8)));
typedef float f32x16 __attribute__((ext_vector_type(16)));

__device__ __forceinline__ unsigned short f2b(float f) {
    union { __hip_bfloat16 b; unsigned short u; } v;
    v.b = __float2bfloat16(f);
    return v.u;
}

// ---- scatter: set presence bit (atomicOr = order-independent) -----------
__global__ __launch_bounds__(256) void scatter_or_k(
    const int4* __restrict__ coords, unsigned int* __restrict__ mask, int n)
{
    int i = blockIdx.x * 256 + threadIdx.x;
    if (i < n) {
        int4 c = coords[i];
        int col = (c.x * S0 + c.y) * S1 + c.z;
        atomicOr(&mask[col], 1u << c.w);
    }
}

// ---- scanA: per-256-col block popcount sums; block 0 also packs weights -
__global__ __launch_bounds__(256) void scanA_k(
    const unsigned int* __restrict__ mask, int* __restrict__ bsum,
    const float* __restrict__ weight, short8* __restrict__ bfrag)
{
    int t = threadIdx.x;
    int pc = __popc(mask[blockIdx.x * 256 + t]);
#pragma unroll
    for (int m = 32; m > 0; m >>= 1) pc += __shfl_xor(pc, m, 64);
    __shared__ int red[4];
    if ((t & 63) == 0) red[t >> 6] = pc;
    __syncthreads();
    if (t == 0) bsum[blockIdx.x] = red[0] + red[1] + red[2] + red[3];

    // fold-in: MFMA B-fragment pack (block 0, one wave)
    if (blockIdx.x == 0 && t < 64) {
        int half = t >> 5;
        int col  = t & 31;
#pragma unroll
        for (int k = 0; k < 9; ++k)
#pragma unroll
            for (int h = 0; h < 2; ++h) {
                short8 fr;
#pragma unroll
                for (int j = 0; j < 8; ++j) {
                    int ic = h * 16 + half * 8 + j;
                    fr[j] = (short)f2b(weight[k * (CH * CH) + ic * CH + col]);
                }
                bfrag[(k * 2 + h) * 64 + t] = fr;
            }
    }
}

// ---- scanBC: tab[col] = {mask, global exclusive rank base} --------------
// each block sums bsum[0..bid-1] (5.4KB broadcast) + local 256-col prefix
__global__ __launch_bounds__(256) void scanBC_k(
    const unsigned int* __restrict__ mask, const int* __restrict__ bsum,
    uint2* __restrict__ tab)
{
    int t = threadIdx.x;
    int b = blockIdx.x;

    int partial = 0;
    for (int j = t; j < b; j += 256) partial += bsum[j];
#pragma unroll
    for (int m = 32; m > 0; m >>= 1) partial += __shfl_xor(partial, m, 64);
    __shared__ int red[4];
    if ((t & 63) == 0) red[t >> 6] = partial;
    __syncthreads();
    int base = red[0] + red[1] + red[2] + red[3];

    int col = b * 256 + t;
    unsigned int m = mask[col];
    int pc = __popc(m);
    __shared__ int sa[256], sb[256];
    sa[t] = pc; __syncthreads();
    int* src = sa; int* dst = sb;
#pragma unroll
    for (int off = 1; off < 256; off <<= 1) {
        dst[t] = src[t] + (t >= off ? src[t - off] : 0);
        __syncthreads();
        int* tmp = src; src = dst; dst = tmp;
    }
    int excl = src[t] - pc + base;
    tab[col] = make_uint2(m, (unsigned int)excl);
}

// ---- rank: pinfo[rank]={i,lin} (scatter into L2) + rankof[i] (coalesced) -
__global__ __launch_bounds__(256) void rank_k(
    const int4*  __restrict__ coords,
    const uint2* __restrict__ tab,
    uint2*       __restrict__ pinfo,
    int*         __restrict__ rankof,
    int n)
{
    int i = blockIdx.x * 256 + threadIdx.x;
    if (i >= n) return;
    int4 c = coords[i];
    int col = (c.x * S0 + c.y) * S1 + c.z;
    int lin = col * 32 + c.w;
    uint2 tv = tab[col];
    int rank = (int)tv.y + __popc(tv.x & ((1u << c.w) - 1u));
    pinfo[rank] = make_uint2((unsigned int)i, (unsigned int)lin);
    rankof[i] = rank;
}

// ---- pack: coalesced featb write, full-line scattered feature reads -----
__global__ __launch_bounds__(256) void pack_k(
    const float* __restrict__ features,
    const uint2* __restrict__ pinfo,
    unsigned short* __restrict__ featb,  // [rank][32] bf16
    int n)
{
    int t = threadIdx.x;
    int row = blockIdx.x * 32 + (t >> 3);   // 32 rows per block
    int j = t & 7;                          // 8 lanes x 16B = one 128B row
    if (row >= n) return;
    unsigned int orig = pinfo[row].x;
    float4 f = ((const float4*)(features + (size_t)orig * CH))[j];
    ushort4 u;
    u.x = f2b(f.x); u.y = f2b(f.y); u.z = f2b(f.z); u.w = f2b(f.w);
    ((ushort4*)(featb + (size_t)row * CH))[j] = u;
}

// ---- conv on rank-sorted points: wave = 32 consecutive ranks ------------
__global__ __launch_bounds__(256) void conv_sorted_k(
    const unsigned short* __restrict__ featb,
    const uint2* __restrict__ pinfo,
    const uint2* __restrict__ tab,
    const short8* __restrict__ bfrag,
    unsigned short* __restrict__ xout,   // bf16 x, rank order [n][32]
    float*        __restrict__ stats_part, // [gridDim.x][64]
    int n, int ntile)
{
    // bijective XCD-chunked swizzle (m204)
    int nwg = gridDim.x;
    int bid = blockIdx.x;
    int q = nwg >> 3, r = nwg & 7;
    int xcd = bid & 7, sidx = bid >> 3;
    int blk = (xcd < r ? xcd * (q + 1) : r * (q + 1) + (xcd - r) * q) + sidx;

    int tid  = threadIdx.x;
    int lane = tid & 63;
    int wv   = tid >> 6;
    int half = lane >> 5;
    int col  = lane & 31;

    short8 B[9][2];
#pragma unroll
    for (int t = 0; t < 9; ++t) {
        B[t][0] = bfrag[(t * 2 + 0) * 64 + lane];
        B[t][1] = bfrag[(t * 2 + 1) * 64 + lane];
    }

    int tile = blk * 4 + wv;
    bool tlive = (tile < ntile);
    int p  = tile * 32 + col;
    bool live = tlive && (p < n);
    int pc = live ? p : 0;

    uint2 pi = pinfo[pc];
    int lin = (int)pi.y;
    int c2 = lin & 31;
    int colv = lin >> 5;
    int c0 = (lin / SLAB) % S0;

    // phase 1: 3 table loads (2.76 MB, L2-resident) -> 9 ranks via popcount
    int nbr[9];
#pragma unroll
    for (int d0 = 0; d0 < 3; ++d0) {
        int n0 = c0 + d0 - 1;
        bool v0 = (n0 >= 0) & (n0 < S0) & live;
        uint2 tv = v0 ? tab[colv + (d0 - 1) * S1] : make_uint2(0u, 0u);
#pragma unroll
        for (int d2 = 0; d2 < 3; ++d2) {
            int n2 = c2 + d2 - 1;
            int rk = -1;
            if (v0 && n2 >= 0 && n2 < S2 && ((tv.x >> n2) & 1u))
                rk = (int)tv.y + __popc(tv.x & ((1u << n2) - 1u));
            nbr[d0 * 3 + d2] = rk;
        }
    }

    bool act[9];
#pragma unroll
    for (int t = 0; t < 9; ++t) act[t] = (__any(nbr[t] >= 0) != 0);

    // phase 2: staged bf16 fragment gathers (rank-local after sort)
    short8 A0[9], A1[9];
#pragma unroll
    for (int t = 0; t < 9; ++t) {
        short8 z;
#pragma unroll
        for (int j = 0; j < 8; ++j) z[j] = 0;
        A0[t] = z; A1[t] = z;
        int nb = nbr[t];
        if (nb >= 0) {
            const short* fp = (const short*)featb + (size_t)nb * CH;
            A0[t] = *(const short8*)(fp + half * 8);
            A1[t] = *(const short8*)(fp + 16 + half * 8);
        }
    }

    // phase 3: MFMAs, skipping wave-dead taps
    f32x16 acc;
#pragma unroll
    for (int i = 0; i < 16; ++i) acc[i] = 0.f;
#pragma unroll
    for (int t = 0; t < 9; ++t) {
        if (act[t]) {
            acc = __builtin_amdgcn_mfma_f32_32x32x16_bf16(A0[t], B[t][0], acc, 0, 0, 0);
            acc = __builtin_amdgcn_mfma_f32_32x32x16_bf16(A1[t], B[t][1], acc, 0, 0, 0);
        }
    }

    // epilogue: LeakyReLU + bf16 coalesced store (rank order) + stats
    // C/D layout: col = lane&31, row = (r&3) + 8*(r>>2) + 4*half
    float s = 0.f, qq = 0.f;
#pragma unroll
    for (int i = 0; i < 16; ++i) {
        float v = acc[i];
        v = v >= 0.f ? v : SLOPE * v;
        int row = (i & 3) + 8 * (i >> 2) + 4 * half;
        int prow = tile * 32 + row;
        if (tlive && prow < n) {
            xout[(size_t)prow * CH + col] = f2b(v);
            s += v; qq += v * v;
        }
    }

    s  += __shfl_xor(s, 32);
    qq += __shfl_xor(qq, 32);

    __shared__ float lsum[4][32];
    __shared__ float lsq[4][32];
    if (lane < 32) { lsum[wv][col] = s; lsq[wv][col] = qq; }
    __syncthreads();
    if (tid < 32) {
        stats_part[(size_t)bid * 64 + tid] =
            lsum[0][tid] + lsum[1][tid] + lsum[2][tid] + lsum[3][tid];
    } else if (tid < 64) {
        int cc = tid - 32;
        stats_part[(size_t)bid * 64 + tid] =
            lsq[0][cc] + lsq[1][cc] + lsq[2][cc] + lsq[3][cc];
    }
}

// ---- deterministic partial reduce ---------------------------------------
__global__ __launch_bounds__(256) void reduce_stats_k(
    const float* __restrict__ part, float* __restrict__ stats, int nb)
{
    int c = blockIdx.x;            // 0..63
    float s = 0.f;
    for (int i = threadIdx.x; i < nb; i += 256)
        s += part[(size_t)i * 64 + c];
#pragma unroll
    for (int m = 32; m > 0; m >>= 1) s += __shfl_xor(s, m, 64);
    __shared__ float red[4];
    int wv = threadIdx.x >> 6;
    if ((threadIdx.x & 63) == 0) red[wv] = s;
    __syncthreads();
    if (threadIdx.x == 0) stats[c] = red[0] + red[1] + red[2] + red[3];
}

// ---- BN normalize: gather xb by rank, fully-coalesced fp32 out write ----
__global__ __launch_bounds__(256) void bn_gather_k(
    const unsigned short* __restrict__ xb,
    const int*   __restrict__ rankof,
    const float* __restrict__ stats,
    const float* __restrict__ gamma,
    const float* __restrict__ beta,
    float* __restrict__ out,
    int n)
{
    int total = n * 4;                        // (orig row, 8-ch slot) pairs
    int stride = gridDim.x * blockDim.x;      // multiple of 4
    int g = blockIdx.x * blockDim.x + threadIdx.x;
    int c8 = g & 3;

    float scale[8], shift[8];
    float rn = 1.0f / (float)n;
#pragma unroll
    for (int j = 0; j < 8; ++j) {
        int oc = c8 * 8 + j;
        float m  = stats[oc] * rn;
        float vv = stats[CH + oc] * rn - m * m;
        float iv = rsqrtf(vv + EPS) * gamma[oc];
        scale[j] = iv;
        shift[j] = beta[oc] - m * iv;
    }

    const short8* x8 = (const short8*)xb;
    for (; g < total; g += stride) {
        int i = g >> 2;                       // original row
        int rank = rankof[i];                 // broadcast across 4 lanes
        short8 v = x8[(size_t)rank * 4 + c8]; // gather, full 128B line per 4 lanes
        float f[8];
#pragma unroll
        for (int j = 0; j < 8; ++j) {
            union { unsigned int u; float f; } w;
            w.u = ((unsigned int)(unsigned short)v[j]) << 16;
            f[j] = fmaf(w.f, scale[j], shift[j]);
        }
        float4* o = (float4*)(out + (size_t)i * CH + c8 * 8);  // coalesced
        o[0] = make_float4(f[0], f[1], f[2], f[3]);
        o[1] = make_float4(f[4], f[5], f[6], f[7]);
    }
}

extern "C" void kernel_launch(void* const* d_in, const int* in_sizes, int n_in,
                              void* d_out, int out_size, void* d_ws, size_t ws_size,
                              hipStream_t stream)
{
    const float* features = (const float*)d_in[0];
    const int4*  coords   = (const int4*)d_in[1];
    const float* weight   = (const float*)d_in[2];
    const float* gamma    = (const float*)d_in[3];
    const float* beta     = (const float*)d_in[4];
    float* out = (float*)d_out;

    int n = in_sizes[0] / CH;            // 400000
    int ntile = (n + 31) / 32;           // 12500
    int conv_blocks = (ntile + 3) / 4;   // 3125

    // ws layout (256 B aligned sections)
    char* w = (char*)d_ws;
    unsigned int* mask = (unsigned int*)w;  w += (size_t)NCOL * 4;            // 1.38 MB
    uint2* tab = (uint2*)w;                 w += (size_t)NCOL * 8;            // 2.76 MB
    int* bsum = (int*)w;                    w += ((size_t)SCAN_BLKS * 4 + 255) & ~(size_t)255;
    uint2* pinfo = (uint2*)w;               w += (size_t)n * 8;               // 3.2 MB
    int* rankof = (int*)w;                  w += (size_t)n * 4;               // 1.6 MB
    unsigned short* featb = (unsigned short*)w; w += (size_t)n * CH * 2;      // 25.6 MB
    unsigned short* xout = (unsigned short*)w;  w += (size_t)n * CH * 2;      // 25.6 MB
    float* stats_part = (float*)w;          w += (size_t)conv_blocks * 64 * 4;
    short8* bfrag = (short8*)w;             w += 9 * 2 * 64 * sizeof(short8);
    float* stats = (float*)w;

    hipMemsetAsync(mask, 0, (size_t)NCOL * 4, stream);

    scatter_or_k<<<(n + 255) / 256, 256, 0, stream>>>(coords, mask, n);
    scanA_k<<<SCAN_BLKS, 256, 0, stream>>>(mask, bsum, weight, bfrag);
    scanBC_k<<<SCAN_BLKS, 256, 0, stream>>>(mask, bsum, tab);
    rank_k<<<(n + 255) / 256, 256, 0, stream>>>(coords, tab, pinfo, rankof, n);
    pack_k<<<(n + 31) / 32, 256, 0, stream>>>(features, pinfo, featb, n);

    conv_sorted_k<<<conv_blocks, 256, 0, stream>>>(
        featb, pinfo, tab, bfrag, xout, stats_part, n, ntile);

    reduce_stats_k<<<64, 256, 0, stream>>>(stats_part, stats, conv_blocks);

    bn_gather_k<<<2048, 256, 0, stream>>>(xout, rankof, stats, gamma, beta, out, n);
}

// Round 8
// 112.350 us; speedup vs baseline: 1.1879x; 1.0020x over previous
//
#include <hip/hip_runtime.h>
#include <hip/hip_bf16.h>

#define S0 480
#define S1 360
#define S2 32
#define SLAB (S1 * S2)                 // 11520
#define CH 32
#define EPS 1e-5f
#define SLOPE 0.01f

#define NCOL (2 * S0 * S1)             // 345600 columns (b,c0,c1)
#define SCAN_BLKS (NCOL / 256)         // 1350

typedef short short8 __attribute__((ext_vector_type(8)));
typedef float f32x16 __attribute__((ext_vector_type(16)));

__device__ __forceinline__ unsigned short f2b(float f) {
    union { __hip_bfloat16 b; unsigned short u; } v;
    v.b = __float2bfloat16(f);
    return v.u;
}

// ---- clear mask: rocclr fillBuffer ran at 35 GB/s (39us!) -- DIY ---------
__global__ __launch_bounds__(256) void clear_mask_k(uint4* __restrict__ mask)
{
    int i = blockIdx.x * 256 + threadIdx.x;
    if (i < NCOL / 4) mask[i] = make_uint4(0u, 0u, 0u, 0u);
}

// ---- scatter: set presence bit (atomicOr = order-independent) -----------
__global__ __launch_bounds__(256) void scatter_or_k(
    const int4* __restrict__ coords, unsigned int* __restrict__ mask, int n)
{
    int i = blockIdx.x * 256 + threadIdx.x;
    if (i < n) {
        int4 c = coords[i];
        int col = (c.x * S0 + c.y) * S1 + c.z;
        atomicOr(&mask[col], 1u << c.w);
    }
}

// ---- scanA: per-256-col block popcount sums; block 0 also packs weights -
__global__ __launch_bounds__(256) void scanA_k(
    const unsigned int* __restrict__ mask, int* __restrict__ bsum,
    const float* __restrict__ weight, short8* __restrict__ bfrag)
{
    int t = threadIdx.x;
    int pc = __popc(mask[blockIdx.x * 256 + t]);
#pragma unroll
    for (int m = 32; m > 0; m >>= 1) pc += __shfl_xor(pc, m, 64);
    __shared__ int red[4];
    if ((t & 63) == 0) red[t >> 6] = pc;
    __syncthreads();
    if (t == 0) bsum[blockIdx.x] = red[0] + red[1] + red[2] + red[3];

    // fold-in: MFMA B-fragment pack (block 0, one wave)
    if (blockIdx.x == 0 && t < 64) {
        int half = t >> 5;
        int col  = t & 31;
#pragma unroll
        for (int k = 0; k < 9; ++k)
#pragma unroll
            for (int h = 0; h < 2; ++h) {
                short8 fr;
#pragma unroll
                for (int j = 0; j < 8; ++j) {
                    int ic = h * 16 + half * 8 + j;
                    fr[j] = (short)f2b(weight[k * (CH * CH) + ic * CH + col]);
                }
                bfrag[(k * 2 + h) * 64 + t] = fr;
            }
    }
}

// ---- scanBC: tab[col] = {mask, global exclusive rank base} --------------
__global__ __launch_bounds__(256) void scanBC_k(
    const unsigned int* __restrict__ mask, const int* __restrict__ bsum,
    uint2* __restrict__ tab)
{
    int t = threadIdx.x;
    int b = blockIdx.x;

    int partial = 0;
    for (int j = t; j < b; j += 256) partial += bsum[j];
#pragma unroll
    for (int m = 32; m > 0; m >>= 1) partial += __shfl_xor(partial, m, 64);
    __shared__ int red[4];
    if ((t & 63) == 0) red[t >> 6] = partial;
    __syncthreads();
    int base = red[0] + red[1] + red[2] + red[3];

    int col = b * 256 + t;
    unsigned int m = mask[col];
    int pc = __popc(m);
    __shared__ int sa[256], sb[256];
    sa[t] = pc; __syncthreads();
    int* src = sa; int* dst = sb;
#pragma unroll
    for (int off = 1; off < 256; off <<= 1) {
        dst[t] = src[t] + (t >= off ? src[t - off] : 0);
        __syncthreads();
        int* tmp = src; src = dst; dst = tmp;
    }
    int excl = src[t] - pc + base;
    tab[col] = make_uint2(m, (unsigned int)excl);
}

// ---- rank: pinfo[rank]={i,lin} (scatter into L2) + rankof[i] (coalesced) -
__global__ __launch_bounds__(256) void rank_k(
    const int4*  __restrict__ coords,
    const uint2* __restrict__ tab,
    uint2*       __restrict__ pinfo,
    int*         __restrict__ rankof,
    int n)
{
    int i = blockIdx.x * 256 + threadIdx.x;
    if (i >= n) return;
    int4 c = coords[i];
    int col = (c.x * S0 + c.y) * S1 + c.z;
    int lin = col * 32 + c.w;
    uint2 tv = tab[col];
    int rank = (int)tv.y + __popc(tv.x & ((1u << c.w) - 1u));
    pinfo[rank] = make_uint2((unsigned int)i, (unsigned int)lin);
    rankof[i] = rank;
}

// ---- pack: coalesced featb write, full-line scattered feature reads -----
__global__ __launch_bounds__(256) void pack_k(
    const float* __restrict__ features,
    const uint2* __restrict__ pinfo,
    unsigned short* __restrict__ featb,  // [rank][32] bf16
    int n)
{
    int t = threadIdx.x;
    int row = blockIdx.x * 32 + (t >> 3);   // 32 rows per block
    int j = t & 7;                          // 8 lanes x 16B = one 128B row
    if (row >= n) return;
    unsigned int orig = pinfo[row].x;
    float4 f = ((const float4*)(features + (size_t)orig * CH))[j];
    ushort4 u;
    u.x = f2b(f.x); u.y = f2b(f.y); u.z = f2b(f.z); u.w = f2b(f.w);
    ((ushort4*)(featb + (size_t)row * CH))[j] = u;
}

// ---- conv on rank-sorted points: wave = 32 consecutive ranks ------------
__global__ __launch_bounds__(256) void conv_sorted_k(
    const unsigned short* __restrict__ featb,
    const uint2* __restrict__ pinfo,
    const uint2* __restrict__ tab,
    const short8* __restrict__ bfrag,
    unsigned short* __restrict__ xout,   // bf16 x, rank order [n][32]
    float*        __restrict__ stats_part, // [gridDim.x][64]
    int n, int ntile)
{
    // bijective XCD-chunked swizzle (m204)
    int nwg = gridDim.x;
    int bid = blockIdx.x;
    int q = nwg >> 3, r = nwg & 7;
    int xcd = bid & 7, sidx = bid >> 3;
    int blk = (xcd < r ? xcd * (q + 1) : r * (q + 1) + (xcd - r) * q) + sidx;

    int tid  = threadIdx.x;
    int lane = tid & 63;
    int wv   = tid >> 6;
    int half = lane >> 5;
    int col  = lane & 31;

    short8 B[9][2];
#pragma unroll
    for (int t = 0; t < 9; ++t) {
        B[t][0] = bfrag[(t * 2 + 0) * 64 + lane];
        B[t][1] = bfrag[(t * 2 + 1) * 64 + lane];
    }

    int tile = blk * 4 + wv;
    bool tlive = (tile < ntile);
    int p  = tile * 32 + col;
    bool live = tlive && (p < n);
    int pc = live ? p : 0;

    uint2 pi = pinfo[pc];
    int lin = (int)pi.y;
    int c2 = lin & 31;
    int colv = lin >> 5;
    int c0 = (lin / SLAB) % S0;

    // phase 1: 3 table loads (2.76 MB, L2-resident) -> 9 ranks via popcount
    int nbr[9];
#pragma unroll
    for (int d0 = 0; d0 < 3; ++d0) {
        int n0 = c0 + d0 - 1;
        bool v0 = (n0 >= 0) & (n0 < S0) & live;
        uint2 tv = v0 ? tab[colv + (d0 - 1) * S1] : make_uint2(0u, 0u);
#pragma unroll
        for (int d2 = 0; d2 < 3; ++d2) {
            int n2 = c2 + d2 - 1;
            int rk = -1;
            if (v0 && n2 >= 0 && n2 < S2 && ((tv.x >> n2) & 1u))
                rk = (int)tv.y + __popc(tv.x & ((1u << n2) - 1u));
            nbr[d0 * 3 + d2] = rk;
        }
    }

    bool act[9];
#pragma unroll
    for (int t = 0; t < 9; ++t) act[t] = (__any(nbr[t] >= 0) != 0);

    // phase 2: staged bf16 fragment gathers (rank-local after sort)
    short8 A0[9], A1[9];
#pragma unroll
    for (int t = 0; t < 9; ++t) {
        short8 z;
#pragma unroll
        for (int j = 0; j < 8; ++j) z[j] = 0;
        A0[t] = z; A1[t] = z;
        int nb = nbr[t];
        if (nb >= 0) {
            const short* fp = (const short*)featb + (size_t)nb * CH;
            A0[t] = *(const short8*)(fp + half * 8);
            A1[t] = *(const short8*)(fp + 16 + half * 8);
        }
    }

    // phase 3: MFMAs, skipping wave-dead taps
    f32x16 acc;
#pragma unroll
    for (int i = 0; i < 16; ++i) acc[i] = 0.f;
#pragma unroll
    for (int t = 0; t < 9; ++t) {
        if (act[t]) {
            acc = __builtin_amdgcn_mfma_f32_32x32x16_bf16(A0[t], B[t][0], acc, 0, 0, 0);
            acc = __builtin_amdgcn_mfma_f32_32x32x16_bf16(A1[t], B[t][1], acc, 0, 0, 0);
        }
    }

    // epilogue: LeakyReLU + bf16 coalesced store (rank order) + stats
    // C/D layout: col = lane&31, row = (r&3) + 8*(r>>2) + 4*half
    float s = 0.f, qq = 0.f;
#pragma unroll
    for (int i = 0; i < 16; ++i) {
        float v = acc[i];
        v = v >= 0.f ? v : SLOPE * v;
        int row = (i & 3) + 8 * (i >> 2) + 4 * half;
        int prow = tile * 32 + row;
        if (tlive && prow < n) {
            xout[(size_t)prow * CH + col] = f2b(v);
            s += v; qq += v * v;
        }
    }

    s  += __shfl_xor(s, 32);
    qq += __shfl_xor(qq, 32);

    __shared__ float lsum[4][32];
    __shared__ float lsq[4][32];
    if (lane < 32) { lsum[wv][col] = s; lsq[wv][col] = qq; }
    __syncthreads();
    if (tid < 32) {
        stats_part[(size_t)bid * 64 + tid] =
            lsum[0][tid] + lsum[1][tid] + lsum[2][tid] + lsum[3][tid];
    } else if (tid < 64) {
        int cc = tid - 32;
        stats_part[(size_t)bid * 64 + tid] =
            lsq[0][cc] + lsq[1][cc] + lsq[2][cc] + lsq[3][cc];
    }
}

// ---- deterministic partial reduce ---------------------------------------
__global__ __launch_bounds__(256) void reduce_stats_k(
    const float* __restrict__ part, float* __restrict__ stats, int nb)
{
    int c = blockIdx.x;            // 0..63
    float s = 0.f;
    for (int i = threadIdx.x; i < nb; i += 256)
        s += part[(size_t)i * 64 + c];
#pragma unroll
    for (int m = 32; m > 0; m >>= 1) s += __shfl_xor(s, m, 64);
    __shared__ float red[4];
    int wv = threadIdx.x >> 6;
    if ((threadIdx.x & 63) == 0) red[wv] = s;
    __syncthreads();
    if (threadIdx.x == 0) stats[c] = red[0] + red[1] + red[2] + red[3];
}

// ---- BN normalize: gather xb by rank, fully-coalesced fp32 out write ----
__global__ __launch_bounds__(256) void bn_gather_k(
    const unsigned short* __restrict__ xb,
    const int*   __restrict__ rankof,
    const float* __restrict__ stats,
    const float* __restrict__ gamma,
    const float* __restrict__ beta,
    float* __restrict__ out,
    int n)
{
    int total = n * 4;                        // (orig row, 8-ch slot) pairs
    int stride = gridDim.x * blockDim.x;      // multiple of 4
    int g = blockIdx.x * blockDim.x + threadIdx.x;
    int c8 = g & 3;

    float scale[8], shift[8];
    float rn = 1.0f / (float)n;
#pragma unroll
    for (int j = 0; j < 8; ++j) {
        int oc = c8 * 8 + j;
        float m  = stats[oc] * rn;
        float vv = stats[CH + oc] * rn - m * m;
        float iv = rsqrtf(vv + EPS) * gamma[oc];
        scale[j] = iv;
        shift[j] = beta[oc] - m * iv;
    }

    const short8* x8 = (const short8*)xb;
    for (; g < total; g += stride) {
        int i = g >> 2;                       // original row
        int rank = rankof[i];                 // broadcast across 4 lanes
        short8 v = x8[(size_t)rank * 4 + c8]; // gather, full 128B line per 4 lanes
        float f[8];
#pragma unroll
        for (int j = 0; j < 8; ++j) {
            union { unsigned int u; float f; } w;
            w.u = ((unsigned int)(unsigned short)v[j]) << 16;
            f[j] = fmaf(w.f, scale[j], shift[j]);
        }
        float4* o = (float4*)(out + (size_t)i * CH + c8 * 8);  // coalesced
        o[0] = make_float4(f[0], f[1], f[2], f[3]);
        o[1] = make_float4(f[4], f[5], f[6], f[7]);
    }
}

extern "C" void kernel_launch(void* const* d_in, const int* in_sizes, int n_in,
                              void* d_out, int out_size, void* d_ws, size_t ws_size,
                              hipStream_t stream)
{
    const float* features = (const float*)d_in[0];
    const int4*  coords   = (const int4*)d_in[1];
    const float* weight   = (const float*)d_in[2];
    const float* gamma    = (const float*)d_in[3];
    const float* beta     = (const float*)d_in[4];
    float* out = (float*)d_out;

    int n = in_sizes[0] / CH;            // 400000
    int ntile = (n + 31) / 32;           // 12500
    int conv_blocks = (ntile + 3) / 4;   // 3125

    // ws layout (256 B aligned sections)
    char* w = (char*)d_ws;
    unsigned int* mask = (unsigned int*)w;  w += (size_t)NCOL * 4;            // 1.38 MB
    uint2* tab = (uint2*)w;                 w += (size_t)NCOL * 8;            // 2.76 MB
    int* bsum = (int*)w;                    w += ((size_t)SCAN_BLKS * 4 + 255) & ~(size_t)255;
    uint2* pinfo = (uint2*)w;               w += (size_t)n * 8;               // 3.2 MB
    int* rankof = (int*)w;                  w += (size_t)n * 4;               // 1.6 MB
    unsigned short* featb = (unsigned short*)w; w += (size_t)n * CH * 2;      // 25.6 MB
    unsigned short* xout = (unsigned short*)w;  w += (size_t)n * CH * 2;      // 25.6 MB
    float* stats_part = (float*)w;          w += (size_t)conv_blocks * 64 * 4;
    short8* bfrag = (short8*)w;             w += 9 * 2 * 64 * sizeof(short8);
    float* stats = (float*)w;

    clear_mask_k<<<(NCOL / 4 + 255) / 256, 256, 0, stream>>>((uint4*)mask);

    scatter_or_k<<<(n + 255) / 256, 256, 0, stream>>>(coords, mask, n);
    scanA_k<<<SCAN_BLKS, 256, 0, stream>>>(mask, bsum, weight, bfrag);
    scanBC_k<<<SCAN_BLKS, 256, 0, stream>>>(mask, bsum, tab);
    rank_k<<<(n + 255) / 256, 256, 0, stream>>>(coords, tab, pinfo, rankof, n);
    pack_k<<<(n + 31) / 32, 256, 0, stream>>>(features, pinfo, featb, n);

    conv_sorted_k<<<conv_blocks, 256, 0, stream>>>(
        featb, pinfo, tab, bfrag, xout, stats_part, n, ntile);

    reduce_stats_k<<<64, 256, 0, stream>>>(stats_part, stats, conv_blocks);

    bn_gather_k<<<2048, 256, 0, stream>>>(xout, rankof, stats, gamma, beta, out, n);
}

// Round 9
// 110.286 us; speedup vs baseline: 1.2101x; 1.0187x over previous
//
#include <hip/hip_runtime.h>
#include <hip/hip_bf16.h>

#define S0 480
#define S1 360
#define S2 32
#define SLAB (S1 * S2)                 // 11520
#define CH 32
#define EPS 1e-5f
#define SLOPE 0.01f

#define NCOL (2 * S0 * S1)             // 345600 columns (b,c0,c1)
#define SCAN_BLKS (NCOL / 256)         // 1350

typedef short short8 __attribute__((ext_vector_type(8)));
typedef float f32x16 __attribute__((ext_vector_type(16)));

__device__ __forceinline__ unsigned short f2b(float f) {
    union { __hip_bfloat16 b; unsigned short u; } v;
    v.b = __float2bfloat16(f);
    return v.u;
}

// ---- clear mask (rocclr fillBuffer is slow for small fills) -------------
__global__ __launch_bounds__(256) void clear_mask_k(uint4* __restrict__ mask)
{
    int i = blockIdx.x * 256 + threadIdx.x;
    if (i < NCOL / 4) mask[i] = make_uint4(0u, 0u, 0u, 0u);
}

// ---- scatter: set presence bit (atomicOr = order-independent) -----------
__global__ __launch_bounds__(256) void scatter_or_k(
    const int4* __restrict__ coords, unsigned int* __restrict__ mask, int n)
{
    int i = blockIdx.x * 256 + threadIdx.x;
    if (i < n) {
        int4 c = coords[i];
        int col = (c.x * S0 + c.y) * S1 + c.z;
        atomicOr(&mask[col], 1u << c.w);
    }
}

// ---- scanA: per-256-col block popcount sums; block 0 also packs weights -
__global__ __launch_bounds__(256) void scanA_k(
    const unsigned int* __restrict__ mask, int* __restrict__ bsum,
    const float* __restrict__ weight, short8* __restrict__ bfrag)
{
    int t = threadIdx.x;
    int pc = __popc(mask[blockIdx.x * 256 + t]);
#pragma unroll
    for (int m = 32; m > 0; m >>= 1) pc += __shfl_xor(pc, m, 64);
    __shared__ int red[4];
    if ((t & 63) == 0) red[t >> 6] = pc;
    __syncthreads();
    if (t == 0) bsum[blockIdx.x] = red[0] + red[1] + red[2] + red[3];

    if (blockIdx.x == 0 && t < 64) {
        int half = t >> 5;
        int col  = t & 31;
#pragma unroll
        for (int k = 0; k < 9; ++k)
#pragma unroll
            for (int h = 0; h < 2; ++h) {
                short8 fr;
#pragma unroll
                for (int j = 0; j < 8; ++j) {
                    int ic = h * 16 + half * 8 + j;
                    fr[j] = (short)f2b(weight[k * (CH * CH) + ic * CH + col]);
                }
                bfrag[(k * 2 + h) * 64 + t] = fr;
            }
    }
}

// ---- scanBC: tab[col] = {mask, global exclusive rank base} --------------
__global__ __launch_bounds__(256) void scanBC_k(
    const unsigned int* __restrict__ mask, const int* __restrict__ bsum,
    uint2* __restrict__ tab)
{
    int t = threadIdx.x;
    int b = blockIdx.x;

    int partial = 0;
    for (int j = t; j < b; j += 256) partial += bsum[j];
#pragma unroll
    for (int m = 32; m > 0; m >>= 1) partial += __shfl_xor(partial, m, 64);
    __shared__ int red[4];
    if ((t & 63) == 0) red[t >> 6] = partial;
    __syncthreads();
    int base = red[0] + red[1] + red[2] + red[3];

    int col = b * 256 + t;
    unsigned int m = mask[col];
    int pc = __popc(m);
    __shared__ int sa[256], sb[256];
    sa[t] = pc; __syncthreads();
    int* src = sa; int* dst = sb;
#pragma unroll
    for (int off = 1; off < 256; off <<= 1) {
        dst[t] = src[t] + (t >= off ? src[t - off] : 0);
        __syncthreads();
        int* tmp = src; src = dst; dst = tmp;
    }
    int excl = src[t] - pc + base;
    tab[col] = make_uint2(m, (unsigned int)excl);
}

// ---- rank: pinfo[rank]={i,lin} (scatter into L2) + rankof[i] (coalesced) -
__global__ __launch_bounds__(256) void rank_k(
    const int4*  __restrict__ coords,
    const uint2* __restrict__ tab,
    uint2*       __restrict__ pinfo,
    int*         __restrict__ rankof,
    int n)
{
    int i = blockIdx.x * 256 + threadIdx.x;
    if (i >= n) return;
    int4 c = coords[i];
    int col = (c.x * S0 + c.y) * S1 + c.z;
    int lin = col * 32 + c.w;
    uint2 tv = tab[col];
    int rank = (int)tv.y + __popc(tv.x & ((1u << c.w) - 1u));
    pinfo[rank] = make_uint2((unsigned int)i, (unsigned int)lin);
    rankof[i] = rank;
}

// ---- pack: XCD-chunked rank ranges (same partition as conv) -------------
__global__ __launch_bounds__(256) void pack_k(
    const float* __restrict__ features,
    const uint2* __restrict__ pinfo,
    unsigned short* __restrict__ featb,  // [rank][32] bf16
    int n, int ntile)
{
    int NB  = gridDim.x;
    int bpx = NB >> 3;                    // blocks per XCD
    int xcd = blockIdx.x & 7;
    int ibx = blockIdx.x >> 3;
    int chunk = (ntile + 7) >> 3;
    int rstart = xcd * chunk * 32;
    int rend   = min((xcd + 1) * chunk, ntile) * 32;
    if (rend > n) rend = n;

    int t = threadIdx.x;
    int j = t & 7;                        // 8 lanes x 16B = one 128B row
    int sub = t >> 3;                     // 32 rows per iteration
    for (int row = rstart + ibx * 32 + sub; row < rend; row += bpx * 32) {
        unsigned int orig = pinfo[row].x;
        float4 f = ((const float4*)(features + (size_t)orig * CH))[j];
        ushort4 u;
        u.x = f2b(f.x); u.y = f2b(f.y); u.z = f2b(f.z); u.w = f2b(f.w);
        ((ushort4*)(featb + (size_t)row * CH))[j] = u;
    }
}

// ---- conv: per-XCD chunks, each wave a run of CONSECUTIVE tiles ---------
__global__ __launch_bounds__(256) void conv_sorted_k(
    const unsigned short* __restrict__ featb,
    const uint2* __restrict__ pinfo,
    const uint2* __restrict__ tab,
    const short8* __restrict__ bfrag,
    unsigned short* __restrict__ xout,   // bf16 x, rank order [n][32]
    float*        __restrict__ stats_part, // [gridDim.x][64]
    int n, int ntile)
{
    int tid  = threadIdx.x;
    int lane = tid & 63;
    int wv   = tid >> 6;
    int half = lane >> 5;
    int col  = lane & 31;

    short8 B[9][2];
#pragma unroll
    for (int t = 0; t < 9; ++t) {
        B[t][0] = bfrag[(t * 2 + 0) * 64 + lane];
        B[t][1] = bfrag[(t * 2 + 1) * 64 + lane];
    }

    // partition: XCD chunk -> per-wave contiguous run of tiles
    int NB  = gridDim.x;
    int bpx = NB >> 3;
    int xcd = blockIdx.x & 7;
    int ibx = blockIdx.x >> 3;
    int chunk = (ntile + 7) >> 3;
    int wpx = bpx * 4;
    int run = (chunk + wpx - 1) / wpx;
    int wix = ibx * 4 + wv;
    int xend = min((xcd + 1) * chunk, ntile);
    int t0 = xcd * chunk + wix * run;
    int t1 = min(t0 + run, xend);

    float s = 0.f, qq = 0.f;

    for (int tile = t0; tile < t1; ++tile) {
        int p = tile * 32 + col;
        bool live = (p < n);
        int pc = live ? p : 0;

        uint2 pi = pinfo[pc];
        int lin = (int)pi.y;
        int c2 = lin & 31;
        int colv = lin >> 5;
        int c0 = (lin / SLAB) % S0;

        int nbr[9];
#pragma unroll
        for (int d0 = 0; d0 < 3; ++d0) {
            int n0 = c0 + d0 - 1;
            bool v0 = (n0 >= 0) & (n0 < S0) & live;
            uint2 tv = v0 ? tab[colv + (d0 - 1) * S1] : make_uint2(0u, 0u);
#pragma unroll
            for (int d2 = 0; d2 < 3; ++d2) {
                int n2 = c2 + d2 - 1;
                int rk = -1;
                if (v0 && n2 >= 0 && n2 < S2 && ((tv.x >> n2) & 1u))
                    rk = (int)tv.y + __popc(tv.x & ((1u << n2) - 1u));
                nbr[d0 * 3 + d2] = rk;
            }
        }

        bool act[9];
#pragma unroll
        for (int t = 0; t < 9; ++t) act[t] = (__any(nbr[t] >= 0) != 0);

        short8 A0[9], A1[9];
#pragma unroll
        for (int t = 0; t < 9; ++t) {
            short8 z;
#pragma unroll
            for (int j = 0; j < 8; ++j) z[j] = 0;
            A0[t] = z; A1[t] = z;
            int nb = nbr[t];
            if (nb >= 0) {
                const short* fp = (const short*)featb + (size_t)nb * CH;
                A0[t] = *(const short8*)(fp + half * 8);
                A1[t] = *(const short8*)(fp + 16 + half * 8);
            }
        }

        f32x16 acc;
#pragma unroll
        for (int i = 0; i < 16; ++i) acc[i] = 0.f;
#pragma unroll
        for (int t = 0; t < 9; ++t) {
            if (act[t]) {
                acc = __builtin_amdgcn_mfma_f32_32x32x16_bf16(A0[t], B[t][0], acc, 0, 0, 0);
                acc = __builtin_amdgcn_mfma_f32_32x32x16_bf16(A1[t], B[t][1], acc, 0, 0, 0);
            }
        }

        // C/D layout: col = lane&31, row = (i&3) + 8*(i>>2) + 4*half
#pragma unroll
        for (int i = 0; i < 16; ++i) {
            float v = acc[i];
            v = v >= 0.f ? v : SLOPE * v;
            int row = (i & 3) + 8 * (i >> 2) + 4 * half;
            int prow = tile * 32 + row;
            if (prow < n) {
                xout[(size_t)prow * CH + col] = f2b(v);
                s += v; qq += v * v;
            }
        }
    }

    s  += __shfl_xor(s, 32);
    qq += __shfl_xor(qq, 32);

    __shared__ float lsum[4][32];
    __shared__ float lsq[4][32];
    if (lane < 32) { lsum[wv][col] = s; lsq[wv][col] = qq; }
    __syncthreads();
    if (tid < 32) {
        stats_part[(size_t)blockIdx.x * 64 + tid] =
            lsum[0][tid] + lsum[1][tid] + lsum[2][tid] + lsum[3][tid];
    } else if (tid < 64) {
        int cc = tid - 32;
        stats_part[(size_t)blockIdx.x * 64 + tid] =
            lsq[0][cc] + lsq[1][cc] + lsq[2][cc] + lsq[3][cc];
    }
}

// ---- deterministic partial reduce ---------------------------------------
__global__ __launch_bounds__(256) void reduce_stats_k(
    const float* __restrict__ part, float* __restrict__ stats, int nb)
{
    int c = blockIdx.x;            // 0..63
    float s = 0.f;
    for (int i = threadIdx.x; i < nb; i += 256)
        s += part[(size_t)i * 64 + c];
#pragma unroll
    for (int m = 32; m > 0; m >>= 1) s += __shfl_xor(s, m, 64);
    __shared__ float red[4];
    int wv = threadIdx.x >> 6;
    if ((threadIdx.x & 63) == 0) red[wv] = s;
    __syncthreads();
    if (threadIdx.x == 0) stats[c] = red[0] + red[1] + red[2] + red[3];
}

// ---- BN normalize: gather xb by rank, fully-coalesced fp32 out write ----
__global__ __launch_bounds__(256) void bn_gather_k(
    const unsigned short* __restrict__ xb,
    const int*   __restrict__ rankof,
    const float* __restrict__ stats,
    const float* __restrict__ gamma,
    const float* __restrict__ beta,
    float* __restrict__ out,
    int n)
{
    int total = n * 4;                        // (orig row, 8-ch slot) pairs
    int stride = gridDim.x * blockDim.x;      // multiple of 4
    int g = blockIdx.x * blockDim.x + threadIdx.x;
    int c8 = g & 3;

    float scale[8], shift[8];
    float rn = 1.0f / (float)n;
#pragma unroll
    for (int j = 0; j < 8; ++j) {
        int oc = c8 * 8 + j;
        float m  = stats[oc] * rn;
        float vv = stats[CH + oc] * rn - m * m;
        float iv = rsqrtf(vv + EPS) * gamma[oc];
        scale[j] = iv;
        shift[j] = beta[oc] - m * iv;
    }

    const short8* x8 = (const short8*)xb;
    for (; g < total; g += stride) {
        int i = g >> 2;                       // original row
        int rank = rankof[i];
        short8 v = x8[(size_t)rank * 4 + c8];
        float f[8];
#pragma unroll
        for (int j = 0; j < 8; ++j) {
            union { unsigned int u; float f; } w;
            w.u = ((unsigned int)(unsigned short)v[j]) << 16;
            f[j] = fmaf(w.f, scale[j], shift[j]);
        }
        float4* o = (float4*)(out + (size_t)i * CH + c8 * 8);  // coalesced
        o[0] = make_float4(f[0], f[1], f[2], f[3]);
        o[1] = make_float4(f[4], f[5], f[6], f[7]);
    }
}

extern "C" void kernel_launch(void* const* d_in, const int* in_sizes, int n_in,
                              void* d_out, int out_size, void* d_ws, size_t ws_size,
                              hipStream_t stream)
{
    const float* features = (const float*)d_in[0];
    const int4*  coords   = (const int4*)d_in[1];
    const float* weight   = (const float*)d_in[2];
    const float* gamma    = (const float*)d_in[3];
    const float* beta     = (const float*)d_in[4];
    float* out = (float*)d_out;

    int n = in_sizes[0] / CH;            // 400000
    int ntile = (n + 31) / 32;           // 12500
    int conv_blocks = 2048;

    // ws layout (256 B aligned sections)
    char* w = (char*)d_ws;
    unsigned int* mask = (unsigned int*)w;  w += (size_t)NCOL * 4;            // 1.38 MB
    uint2* tab = (uint2*)w;                 w += (size_t)NCOL * 8;            // 2.76 MB
    int* bsum = (int*)w;                    w += ((size_t)SCAN_BLKS * 4 + 255) & ~(size_t)255;
    uint2* pinfo = (uint2*)w;               w += (size_t)n * 8;               // 3.2 MB
    int* rankof = (int*)w;                  w += (size_t)n * 4;               // 1.6 MB
    unsigned short* featb = (unsigned short*)w; w += (size_t)n * CH * 2;      // 25.6 MB
    unsigned short* xout = (unsigned short*)w;  w += (size_t)n * CH * 2;      // 25.6 MB
    float* stats_part = (float*)w;          w += (size_t)conv_blocks * 64 * 4;
    short8* bfrag = (short8*)w;             w += 9 * 2 * 64 * sizeof(short8);
    float* stats = (float*)w;

    clear_mask_k<<<(NCOL / 4 + 255) / 256, 256, 0, stream>>>((uint4*)mask);
    scatter_or_k<<<(n + 255) / 256, 256, 0, stream>>>(coords, mask, n);
    scanA_k<<<SCAN_BLKS, 256, 0, stream>>>(mask, bsum, weight, bfrag);
    scanBC_k<<<SCAN_BLKS, 256, 0, stream>>>(mask, bsum, tab);
    rank_k<<<(n + 255) / 256, 256, 0, stream>>>(coords, tab, pinfo, rankof, n);
    pack_k<<<2048, 256, 0, stream>>>(features, pinfo, featb, n, ntile);

    conv_sorted_k<<<conv_blocks, 256, 0, stream>>>(
        featb, pinfo, tab, bfrag, xout, stats_part, n, ntile);

    reduce_stats_k<<<64, 256, 0, stream>>>(stats_part, stats, conv_blocks);

    bn_gather_k<<<2048, 256, 0, stream>>>(xout, rankof, stats, gamma, beta, out, n);
}